// Round 14
// baseline (613.166 us; speedup 1.0000x reference)
//
#include <hip/hip_runtime.h>
#include <hip/hip_bf16.h>
#include <stdint.h>

#define N_NODES 100000
#define N_EDGES 1600000
#define FEAT 128
#define EMB 128
#define N_ROOTS 4096

#define BUCKET_BITS 9
#define BUCKET_NODES 512
#define NBUCK ((N_NODES + BUCKET_NODES - 1) / BUCKET_NODES)  // 196
#define BUCK_CAP 12288
#define BIN_CHUNK 4096
#define NB_BIN ((N_EDGES + BIN_CHUNK - 1) / BIN_CHUNK)       // 391
#define BUCK_SLACK 4096
#define SRCS_CAP (N_EDGES + NBUCK * BUCK_SLACK + 4096)

#define FUSED_LDS 65536

typedef __attribute__((ext_vector_type(4))) float f32x4;
typedef __attribute__((ext_vector_type(8))) short bf16x8;

__device__ __forceinline__ ushort f2b(float f) {
  uint32_t u = __float_as_uint(f);
  uint32_t r = (u + 0x7FFFu + ((u >> 16) & 1u)) >> 16;  // RNE
  return (ushort)r;
}
__device__ __forceinline__ float b2f(ushort b) {
  return __uint_as_float(((uint32_t)b) << 16);
}

__global__ void k_cvt_bf16(const float* __restrict__ in, ushort* __restrict__ out, int n4) {
  int i = blockIdx.x * blockDim.x + threadIdx.x;
  int stride = gridDim.x * blockDim.x;
  for (; i < n4; i += stride) {
    float4 v = ((const float4*)in)[i];
    ushort4 o;
    o.x = f2b(v.x); o.y = f2b(v.y); o.z = f2b(v.z); o.w = f2b(v.w);
    ((ushort4*)out)[i] = o;
  }
}

// W (f32 [K][128]) -> bf16 in MFMA-fragment order: Wf[((ks*8+ct)*64 + lane)*8 + e]
// where k = ks*32 + (lane>>4)*8 + e, c = ct*16 + (lane&15).
__global__ void k_cvtW(const float* __restrict__ W, ushort* __restrict__ Wf, int K) {
  int idx = blockIdx.x * blockDim.x + threadIdx.x;
  if (idx >= K * 128) return;
  int k = idx >> 7, c = idx & 127;
  int ks = k >> 5, kh = (k >> 3) & 3, e = k & 7;
  int ct = c >> 4, rl = c & 15;
  Wf[(size_t)(((ks * 8 + ct) * 64) + kh * 16 + rl) * 8 + e] = f2b(W[idx]);
}

// ---- bucketed CSR build (unchanged) ----
__global__ __launch_bounds__(256) void k_bin(const int* __restrict__ srcA, const int* __restrict__ dstA,
                                             int* __restrict__ bucket_cnt, int* __restrict__ binned) {
  __shared__ int hist[NBUCK];
  __shared__ int lscan[NBUCK];
  __shared__ int rsv[NBUCK];
  __shared__ int lpos[NBUCK];
  __shared__ int ws[4];
  __shared__ int2 ent[BIN_CHUNK];
  int t = threadIdx.x;
  int e0 = blockIdx.x * BIN_CHUNK;
  int cnt = min(BIN_CHUNK, N_EDGES - e0);
  for (int i = t; i < NBUCK; i += 256) hist[i] = 0;
  __syncthreads();
  for (int j = t; j < cnt; j += 256) atomicAdd(&hist[dstA[e0 + j] >> BUCKET_BITS], 1);
  __syncthreads();
  {
    int lane = t & 63, wv = t >> 6;
    int v = (t < NBUCK) ? hist[t] : 0;
    int inc = v;
    for (int d = 1; d < 64; d <<= 1) { int x = __shfl_up(inc, d); if (lane >= d) inc += x; }
    if (lane == 63) ws[wv] = inc;
    __syncthreads();
    int wbase = 0;
    for (int k = 0; k < wv; ++k) wbase += ws[k];
    if (t < NBUCK) {
      int excl = wbase + inc - v;
      lscan[t] = excl;
      lpos[t] = excl;
      rsv[t] = (v > 0) ? atomicAdd(&bucket_cnt[t], v) : 0;
    }
  }
  __syncthreads();
  for (int j = t; j < cnt; j += 256) {
    int s = srcA[e0 + j], d = dstA[e0 + j];
    int p = atomicAdd(&lpos[d >> BUCKET_BITS], 1);
    ent[p] = make_int2(s, d);
  }
  __syncthreads();
  for (int j = t; j < cnt; j += 256) {
    int2 E = ent[j];
    int b = E.y >> BUCKET_BITS;
    int pos = rsv[b] + (j - lscan[b]);
    if (pos < BUCK_CAP)
      binned[b * BUCK_CAP + pos] = (E.x << BUCKET_BITS) | (E.y & (BUCKET_NODES - 1));
  }
}

__global__ __launch_bounds__(256) void k_bucket_scan(const int* __restrict__ bucket_cnt,
                                                     int* __restrict__ bucket_base) {
  __shared__ int ws[4];
  int t = threadIdx.x;
  int lane = t & 63, wv = t >> 6;
  int v = (t < NBUCK) ? bucket_cnt[t] : 0;
  int inc = v;
  for (int d = 1; d < 64; d <<= 1) { int x = __shfl_up(inc, d); if (lane >= d) inc += x; }
  if (lane == 63) ws[wv] = inc;
  __syncthreads();
  int wbase = 0;
  for (int k = 0; k < wv; ++k) wbase += ws[k];
  if (t < NBUCK) bucket_base[t] = (wbase + inc - v) + t * BUCK_SLACK;
}

__global__ __launch_bounds__(512) void k_csr(const int* __restrict__ binned,
                                             const int* __restrict__ bucket_cnt,
                                             const int* __restrict__ bucket_base,
                                             int2* __restrict__ off2, int* __restrict__ srcs) {
  __shared__ int deg[BUCKET_NODES];
  __shared__ int sAb[BUCKET_NODES];
  __shared__ int sBb[BUCKET_NODES];
  __shared__ int pos[BUCKET_NODES];
  __shared__ int epk[BUCK_CAP];
  int b = blockIdx.x;
  int t = threadIdx.x;
  int cnt = min(bucket_cnt[b], BUCK_CAP);
  int gbase = bucket_base[b];
  int n0 = b * BUCKET_NODES;
  int nn = min(BUCKET_NODES, N_NODES - n0);
  deg[t] = 0;
  __syncthreads();
  for (int j = t; j < cnt; j += 512) {
    int p = binned[b * BUCK_CAP + j];
    epk[j] = p;
    atomicAdd(&deg[p & (BUCKET_NODES - 1)], 1);
  }
  __syncthreads();
  int d = deg[t];
  int dp = (d + 7) & ~7;
  int* sA = sAb; int* sB = sBb;
  sA[t] = dp;
  __syncthreads();
  for (int q = 1; q < 512; q <<= 1) {
    int x = sA[t];
    if (t >= q) x += sA[t - q];
    sB[t] = x;
    __syncthreads();
    int* tp = sA; sA = sB; sB = tp;
  }
  int ex = sA[t] - dp;
  pos[t] = ex;
  if (t < nn) off2[n0 + t] = make_int2(gbase + ex, gbase + ex + dp);
  __syncthreads();
  for (int j = t; j < cnt; j += 512) {
    int p = epk[j];
    int q = atomicAdd(&pos[p & (BUCKET_NODES - 1)], 1);
    srcs[gbase + q] = p >> BUCKET_BITS;
  }
  __syncthreads();
  for (int q = ex + d; q < ex + dp; ++q) srcs[gbase + q] = N_NODES;  // zero-row dummies
}

// Fused gather+GEMM layer. Block = 128 nodes, 256 thr, 64KB dyn LDS (2 blocks/CU).
// Phase1: wave w gathers its 32 rows into swizzled LDS A-tile (+ optional xagg copy/store).
// Phase2: MFMA, A from LDS, B from fragment-ordered global Wf.
// Phase3: LDS reused as f32 epi, coalesced bias+resid+store.
template <int K>
__global__ __launch_bounds__(256) void k_fused(
    const ushort* __restrict__ table, const int2* __restrict__ off2, const int* __restrict__ srcs,
    uint32_t* __restrict__ xagg32, int writeXagg, int relu,
    const ushort* __restrict__ Wf, const float* __restrict__ bias,
    const ushort* __restrict__ resid,
    ushort* __restrict__ outb, float* __restrict__ outf, int n)
{
  extern __shared__ char lds[];
  const int AS = K * 2;  // A-tile row stride (bytes)
  int t = threadIdx.x, lane = t & 63, wv = t >> 6;
  int base = blockIdx.x * 128;

  // ---- phase 1: gather (1 wave per node, 2 bf16 cols per lane) ----
  for (int i = 0; i < 32; ++i) {
    int node = base + wv * 32 + i;
    if (node >= n) break;
    int2 se = off2[node];
    int s = __builtin_amdgcn_readfirstlane(se.x);
    int e = __builtin_amdgcn_readfirstlane(se.y);
    float a0 = 0.f, a1 = 0.f;
    int j = s;
    for (; j + 16 <= e; j += 16) {
      int ix[16];
#pragma unroll
      for (int q = 0; q < 16; ++q) ix[q] = srcs[j + q];
      uint32_t u[16];
#pragma unroll
      for (int q = 0; q < 16; ++q)
        u[q] = *(const uint32_t*)(table + (size_t)ix[q] * 128 + lane * 2);
#pragma unroll
      for (int q = 0; q < 16; ++q) {
        if (relu) { uint32_t m = (u[q] >> 15) & 0x00010001u; u[q] &= ~(m * 0xFFFFu); }
        a0 += __uint_as_float(u[q] << 16);
        a1 += __uint_as_float(u[q] & 0xFFFF0000u);
      }
    }
    if (j < e) {  // remainder exactly 8 (padded)
      int ix[8];
#pragma unroll
      for (int q = 0; q < 8; ++q) ix[q] = srcs[j + q];
      uint32_t u[8];
#pragma unroll
      for (int q = 0; q < 8; ++q)
        u[q] = *(const uint32_t*)(table + (size_t)ix[q] * 128 + lane * 2);
#pragma unroll
      for (int q = 0; q < 8; ++q) {
        if (relu) { uint32_t m = (u[q] >> 15) & 0x00010001u; u[q] &= ~(m * 0xFFFFu); }
        a0 += __uint_as_float(u[q] << 16);
        a1 += __uint_as_float(u[q] & 0xFFFF0000u);
      }
    }
    uint32_t pk = (uint32_t)f2b(a0) | ((uint32_t)f2b(a1) << 16);
    int row = node - base;
    *(uint32_t*)(lds + row * AS + ((lane * 4) ^ ((row & 7) << 4))) = pk;
    if (writeXagg) {
      xagg32[(size_t)node * 64 + lane] = pk;
    } else {
      uint32_t pk2 = xagg32[(size_t)node * 64 + lane];
      *(uint32_t*)(lds + row * AS + ((256 + lane * 4) ^ ((row & 7) << 4))) = pk2;
    }
  }

  // ---- phase 2: MFMA (wave w owns rows w*32..w*32+31 — only its own LDS data) ----
  int rl = lane & 15, kh = lane >> 4;
  int r0 = wv * 32 + rl, r1 = r0 + 16;
  f32x4 acc[2][8];
#pragma unroll
  for (int i = 0; i < 2; ++i)
#pragma unroll
    for (int j = 0; j < 8; ++j)
      acc[i][j] = (f32x4){0.f, 0.f, 0.f, 0.f};
  const int nks = K >> 5;
#pragma unroll
  for (int ks = 0; ks < nks; ++ks) {
    int cb = ks * 64 + kh * 16;
    bf16x8 a0 = *(const bf16x8*)(lds + r0 * AS + (cb ^ ((r0 & 7) << 4)));
    bf16x8 a1 = *(const bf16x8*)(lds + r1 * AS + (cb ^ ((r1 & 7) << 4)));
#pragma unroll
    for (int ct = 0; ct < 8; ++ct) {
      bf16x8 b = *(const bf16x8*)(Wf + (size_t)((ks * 8 + ct) * 64 + lane) * 8);
      acc[0][ct] = __builtin_amdgcn_mfma_f32_16x16x32_bf16(a0, b, acc[0][ct], 0, 0, 0);
      acc[1][ct] = __builtin_amdgcn_mfma_f32_16x16x32_bf16(a1, b, acc[1][ct], 0, 0, 0);
    }
  }

  // ---- phase 3: epilogue via LDS (f32 [128] rows, 512B stride, same swizzle) ----
  __syncthreads();  // all waves done with their A-tiles (K=128 epi overlaps other waves' A)
#pragma unroll
  for (int ri = 0; ri < 2; ++ri)
#pragma unroll
    for (int ct = 0; ct < 8; ++ct) {
      int col = (ct << 4) + rl;
#pragma unroll
      for (int j = 0; j < 4; ++j) {
        int row = wv * 32 + ri * 16 + kh * 4 + j;
        *(float*)(lds + row * 512 + ((col * 4) ^ ((row & 7) << 4))) = acc[ri][ct][j];
      }
    }
  __syncthreads();

  int colb = (t & 31) << 2;  // 4-float group
  float4 bv4 = *(const float4*)(bias + colb);
#pragma unroll
  for (int p = 0; p < 16; ++p) {
    int r = (t >> 5) + p * 8;
    int grow = base + r;
    if (grow >= n) continue;
    float4 v = *(const float4*)(lds + r * 512 + ((colb * 4) ^ ((r & 7) << 4)));
    v.x += bv4.x; v.y += bv4.y; v.z += bv4.z; v.w += bv4.w;
    size_t gidx = (size_t)grow * 128 + colb;
    if (resid) {
      ushort4 rr = *(const ushort4*)(resid + gidx);
      v.x += b2f(rr.x); v.y += b2f(rr.y); v.z += b2f(rr.z); v.w += b2f(rr.w);
    }
    if (outf) {
      *(float4*)(outf + gidx) = v;
    } else {
      ushort4 o;
      o.x = f2b(v.x); o.y = f2b(v.y); o.z = f2b(v.z); o.w = f2b(v.w);
      *(ushort4*)(outb + gidx) = o;
    }
  }
}

extern "C" void kernel_launch(void* const* d_in, const int* in_sizes, int n_in,
                              void* d_out, int out_size, void* d_ws, size_t ws_size,
                              hipStream_t stream) {
  const float* x = (const float*)d_in[0];
  const int* ei  = (const int*)d_in[1];
  const int* src = ei;
  const int* dst = ei + N_EDGES;
  const float* Wp[4] = {(const float*)d_in[4], (const float*)d_in[6],
                        (const float*)d_in[8], (const float*)d_in[10]};
  const float* bp[4] = {(const float*)d_in[5], (const float*)d_in[7],
                        (const float*)d_in[9], (const float*)d_in[11]};
  const int Kl[4] = {128, 256, 256, 256};

  char* w = (char*)d_ws;
  auto alloc = [&](size_t bytes) {
    char* p = w;
    w += (bytes + 255) & ~(size_t)255;
    return p;
  };
  ushort* x_bf  = (ushort*)alloc((size_t)(N_NODES + 8) * 128 * 2);  // + zero row
  ushort* hA    = (ushort*)alloc((size_t)(N_NODES + 8) * 128 * 2);  // + zero row
  ushort* hB    = (ushort*)alloc((size_t)(N_NODES + 8) * 128 * 2);  // + zero row
  ushort* xagg  = (ushort*)alloc((size_t)N_NODES * 128 * 2);
  int2*   off2  = (int2*)  alloc((size_t)N_NODES * 8);
  int*    srcs  = (int*)   alloc((size_t)SRCS_CAP * 4);
  int*    binned = (int*)  alloc((size_t)NBUCK * BUCK_CAP * 4);
  int*    bucket_cnt  = (int*)alloc((size_t)NBUCK * 4);
  int*    bucket_base = (int*)alloc((size_t)NBUCK * 4);
  ushort* Wfr[4];
  for (int l = 0; l < 4; ++l) Wfr[l] = (ushort*)alloc((size_t)Kl[l] * 128 * 2);
  if ((size_t)(w - (char*)d_ws) > ws_size) return;

  hipMemsetAsync(bucket_cnt, 0, (size_t)NBUCK * 4, stream);
  hipMemsetAsync(x_bf + (size_t)N_NODES * 128, 0, 256, stream);
  hipMemsetAsync(hA + (size_t)N_NODES * 128, 0, 256, stream);
  hipMemsetAsync(hB + (size_t)N_NODES * 128, 0, 256, stream);
  k_cvt_bf16<<<2048, 256, 0, stream>>>(x, x_bf, N_NODES * 128 / 4);
  for (int l = 0; l < 4; ++l)
    k_cvtW<<<(Kl[l] * 128 + 255) / 256, 256, 0, stream>>>(Wp[l], Wfr[l], Kl[l]);
  k_bin<<<NB_BIN, 256, 0, stream>>>(src, dst, bucket_cnt, binned);
  k_bucket_scan<<<1, 256, 0, stream>>>(bucket_cnt, bucket_base);
  k_csr<<<NBUCK, 512, 0, stream>>>(binned, bucket_cnt, bucket_base, off2, srcs);

  int gfull = (N_NODES + 127) / 128;   // 782
  int groot = (N_ROOTS + 127) / 128;   // 32
  // layer 0: gather x (-> xagg persisted) + GEMM W0 -> hA
  k_fused<128><<<gfull, 256, FUSED_LDS, stream>>>(
      x_bf, off2, srcs, (uint32_t*)xagg, 1, 0, Wfr[0], bp[0], nullptr,
      hA, nullptr, N_NODES);
  // layer 1: gather relu(hA) | xagg -> GEMM W1 + resid hA -> hB
  k_fused<256><<<gfull, 256, FUSED_LDS, stream>>>(
      hA, off2, srcs, (uint32_t*)xagg, 0, 1, Wfr[1], bp[1], hA,
      hB, nullptr, N_NODES);
  // layer 2: hB -> hA
  k_fused<256><<<gfull, 256, FUSED_LDS, stream>>>(
      hB, off2, srcs, (uint32_t*)xagg, 0, 1, Wfr[2], bp[2], hB,
      hA, nullptr, N_NODES);
  // layer 3: roots only -> d_out (f32)
  k_fused<256><<<groot, 256, FUSED_LDS, stream>>>(
      hA, off2, srcs, (uint32_t*)xagg, 0, 1, Wfr[3], bp[3], hA,
      nullptr, (float*)d_out, N_ROOTS);
}

// Round 15
// 364.149 us; speedup vs baseline: 1.6838x; 1.6838x over previous
//
#include <hip/hip_runtime.h>
#include <hip/hip_bf16.h>
#include <stdint.h>

#define N_NODES 100000
#define N_EDGES 1600000
#define FEAT 128
#define EMB 128
#define N_ROOTS 4096

#define BUCKET_BITS 9
#define BUCKET_NODES 512
#define NBUCK ((N_NODES + BUCKET_NODES - 1) / BUCKET_NODES)  // 196
#define BUCK_CAP 12288
#define BIN_CHUNK 4096
#define NB_BIN ((N_EDGES + BIN_CHUNK - 1) / BIN_CHUNK)       // 391
#define BUCK_SLACK 4096
#define SRCS_CAP (N_EDGES + NBUCK * BUCK_SLACK + 4096)

typedef __attribute__((ext_vector_type(4))) float f32x4;
typedef __attribute__((ext_vector_type(8))) short bf16x8;

__device__ __forceinline__ ushort f2b(float f) {
  uint32_t u = __float_as_uint(f);
  uint32_t r = (u + 0x7FFFu + ((u >> 16) & 1u)) >> 16;  // RNE
  return (ushort)r;
}

__global__ void k_cvt_bf16(const float* __restrict__ in, ushort* __restrict__ out, int n4) {
  int i = blockIdx.x * blockDim.x + threadIdx.x;
  int stride = gridDim.x * blockDim.x;
  for (; i < n4; i += stride) {
    float4 v = ((const float4*)in)[i];
    ushort4 o;
    o.x = f2b(v.x); o.y = f2b(v.y); o.z = f2b(v.z); o.w = f2b(v.w);
    ((ushort4*)out)[i] = o;
  }
}

// W (f32 [K][128]) -> bf16 in MFMA-fragment order (verified R14):
// Wf[((ks*8+ct)*64 + kh*16 + rl)*8 + e], k = ks*32+kh*8+e, c = ct*16+rl
__global__ void k_cvtW(const float* __restrict__ W, ushort* __restrict__ Wf, int K) {
  int idx = blockIdx.x * blockDim.x + threadIdx.x;
  if (idx >= K * 128) return;
  int k = idx >> 7, c = idx & 127;
  int ks = k >> 5, kh = (k >> 3) & 3, e = k & 7;
  int ct = c >> 4, rl = c & 15;
  Wf[(size_t)(((ks * 8 + ct) * 64) + kh * 16 + rl) * 8 + e] = f2b(W[idx]);
}

// ---- bucketed CSR build (R11, unchanged) ----
__global__ __launch_bounds__(256) void k_bin(const int* __restrict__ srcA, const int* __restrict__ dstA,
                                             int* __restrict__ bucket_cnt, int* __restrict__ binned) {
  __shared__ int hist[NBUCK];
  __shared__ int lscan[NBUCK];
  __shared__ int rsv[NBUCK];
  __shared__ int lpos[NBUCK];
  __shared__ int ws[4];
  __shared__ int2 ent[BIN_CHUNK];
  int t = threadIdx.x;
  int e0 = blockIdx.x * BIN_CHUNK;
  int cnt = min(BIN_CHUNK, N_EDGES - e0);
  for (int i = t; i < NBUCK; i += 256) hist[i] = 0;
  __syncthreads();
  for (int j = t; j < cnt; j += 256) atomicAdd(&hist[dstA[e0 + j] >> BUCKET_BITS], 1);
  __syncthreads();
  {
    int lane = t & 63, wv = t >> 6;
    int v = (t < NBUCK) ? hist[t] : 0;
    int inc = v;
    for (int d = 1; d < 64; d <<= 1) { int x = __shfl_up(inc, d); if (lane >= d) inc += x; }
    if (lane == 63) ws[wv] = inc;
    __syncthreads();
    int wbase = 0;
    for (int k = 0; k < wv; ++k) wbase += ws[k];
    if (t < NBUCK) {
      int excl = wbase + inc - v;
      lscan[t] = excl;
      lpos[t] = excl;
      rsv[t] = (v > 0) ? atomicAdd(&bucket_cnt[t], v) : 0;
    }
  }
  __syncthreads();
  for (int j = t; j < cnt; j += 256) {
    int s = srcA[e0 + j], d = dstA[e0 + j];
    int p = atomicAdd(&lpos[d >> BUCKET_BITS], 1);
    ent[p] = make_int2(s, d);
  }
  __syncthreads();
  for (int j = t; j < cnt; j += 256) {
    int2 E = ent[j];
    int b = E.y >> BUCKET_BITS;
    int pos = rsv[b] + (j - lscan[b]);
    if (pos < BUCK_CAP)
      binned[b * BUCK_CAP + pos] = (E.x << BUCKET_BITS) | (E.y & (BUCKET_NODES - 1));
  }
}

__global__ __launch_bounds__(256) void k_bucket_scan(const int* __restrict__ bucket_cnt,
                                                     int* __restrict__ bucket_base) {
  __shared__ int ws[4];
  int t = threadIdx.x;
  int lane = t & 63, wv = t >> 6;
  int v = (t < NBUCK) ? bucket_cnt[t] : 0;
  int inc = v;
  for (int d = 1; d < 64; d <<= 1) { int x = __shfl_up(inc, d); if (lane >= d) inc += x; }
  if (lane == 63) ws[wv] = inc;
  __syncthreads();
  int wbase = 0;
  for (int k = 0; k < wv; ++k) wbase += ws[k];
  if (t < NBUCK) bucket_base[t] = (wbase + inc - v) + t * BUCK_SLACK;
}

__global__ __launch_bounds__(512) void k_csr(const int* __restrict__ binned,
                                             const int* __restrict__ bucket_cnt,
                                             const int* __restrict__ bucket_base,
                                             int2* __restrict__ off2, int* __restrict__ srcs) {
  __shared__ int deg[BUCKET_NODES];
  __shared__ int sAb[BUCKET_NODES];
  __shared__ int sBb[BUCKET_NODES];
  __shared__ int pos[BUCKET_NODES];
  __shared__ int epk[BUCK_CAP];
  int b = blockIdx.x;
  int t = threadIdx.x;
  int cnt = min(bucket_cnt[b], BUCK_CAP);
  int gbase = bucket_base[b];
  int n0 = b * BUCKET_NODES;
  int nn = min(BUCKET_NODES, N_NODES - n0);
  deg[t] = 0;
  __syncthreads();
  for (int j = t; j < cnt; j += 512) {
    int p = binned[b * BUCK_CAP + j];
    epk[j] = p;
    atomicAdd(&deg[p & (BUCKET_NODES - 1)], 1);
  }
  __syncthreads();
  int d = deg[t];
  int dp = (d + 7) & ~7;
  int* sA = sAb; int* sB = sBb;
  sA[t] = dp;
  __syncthreads();
  for (int q = 1; q < 512; q <<= 1) {
    int x = sA[t];
    if (t >= q) x += sA[t - q];
    sB[t] = x;
    __syncthreads();
    int* tp = sA; sA = sB; sB = tp;
  }
  int ex = sA[t] - dp;
  pos[t] = ex;
  if (t < nn) off2[n0 + t] = make_int2(gbase + ex, gbase + ex + dp);
  __syncthreads();
  for (int j = t; j < cnt; j += 512) {
    int p = epk[j];
    int q = atomicAdd(&pos[p & (BUCKET_NODES - 1)], 1);
    srcs[gbase + q] = p >> BUCKET_BITS;
  }
  __syncthreads();
  for (int q = ex + d; q < ex + dp; ++q) srcs[gbase + q] = N_NODES;  // zero-row dummies
}

// out[n][128](bf16) = A @ W; A = A0|A1 split at k=128 (optional relu on A0);
// W from fragment-ordered global table (L2-hot, no LDS -> high occupancy).
__global__ __launch_bounds__(256) void k_gemm(
    const ushort* __restrict__ A0, const ushort* __restrict__ A1,
    const ushort* __restrict__ Wf, ushort* __restrict__ out, int n, int K, int relu0)
{
  int lane = threadIdx.x & 63;
  int wv = threadIdx.x >> 6;
  int rowBase = blockIdx.x * 128 + wv * 32;
  int rl = lane & 15;
  int kh = lane >> 4;
  int r0 = rowBase + rl, r1 = r0 + 16;
  int r0c = min(r0, n - 1), r1c = min(r1, n - 1);

  f32x4 acc[2][8];
#pragma unroll
  for (int i = 0; i < 2; ++i)
#pragma unroll
    for (int j = 0; j < 8; ++j)
      acc[i][j] = (f32x4){0.f, 0.f, 0.f, 0.f};

  int nks = K >> 5;
  bf16x8 a0, a1;
  {
    int kof = (kh << 3);
    a0 = *(const bf16x8*)(A0 + (size_t)r0c * 128 + kof);
    a1 = *(const bf16x8*)(A0 + (size_t)r1c * 128 + kof);
  }
  for (int ks = 0; ks < nks; ++ks) {
    bf16x8 na0 = a0, na1 = a1;
    if (ks + 1 < nks) {
      int ksn = ks + 1;
      const ushort* Asrc = (ksn < 4) ? A0 : A1;
      int kof = ((ksn & 3) << 5) + (kh << 3);
      na0 = *(const bf16x8*)(Asrc + (size_t)r0c * 128 + kof);
      na1 = *(const bf16x8*)(Asrc + (size_t)r1c * 128 + kof);
    }
    if (relu0 && ks < 4) {   // relu on bf16: negative -> 0
#pragma unroll
      for (int q = 0; q < 8; ++q) {
        short v0 = a0[q]; a0[q] = (short)(v0 & ~(v0 >> 15));
        short v1 = a1[q]; a1[q] = (short)(v1 & ~(v1 >> 15));
      }
    }
#pragma unroll
    for (int ct = 0; ct < 8; ++ct) {
      bf16x8 b = *(const bf16x8*)(Wf + (size_t)((ks * 8 + ct) * 64 + lane) * 8);
      acc[0][ct] = __builtin_amdgcn_mfma_f32_16x16x32_bf16(a0, b, acc[0][ct], 0, 0, 0);
      acc[1][ct] = __builtin_amdgcn_mfma_f32_16x16x32_bf16(a1, b, acc[1][ct], 0, 0, 0);
    }
    a0 = na0; a1 = na1;
  }
#pragma unroll
  for (int ri = 0; ri < 2; ++ri)
#pragma unroll
    for (int ct = 0; ct < 8; ++ct) {
      int col = (ct << 4) + rl;
#pragma unroll
      for (int j = 0; j < 4; ++j) {
        int row = rowBase + ri * 16 + kh * 4 + j;
        if (row < n) out[(size_t)row * 128 + col] = f2b(acc[ri][ct][j]);
      }
    }
}

// segment sum, padded CSR: 1 wave/node, 2 cols/lane, unroll-16 two-phase (R11)
__global__ __launch_bounds__(256) void k_aggr(
    const ushort* __restrict__ hlin, const int2* __restrict__ off2, const int* __restrict__ srcs,
    const float* __restrict__ bias, ushort* __restrict__ hbf, float* __restrict__ outf,
    int n, int first, int last)
{
  int node = blockIdx.x * 4 + (threadIdx.x >> 6);
  if (node >= n) return;
  int lane = threadIdx.x & 63;
  int2 se = off2[node];
  int s = __builtin_amdgcn_readfirstlane(se.x);
  int e = __builtin_amdgcn_readfirstlane(se.y);
  float a0 = 0.f, a1 = 0.f;
  int j = s;
  for (; j + 16 <= e; j += 16) {
    int ix[16];
#pragma unroll
    for (int q = 0; q < 16; ++q) ix[q] = srcs[j + q];
    uint32_t u[16];
#pragma unroll
    for (int q = 0; q < 16; ++q)
      u[q] = *(const uint32_t*)(hlin + (size_t)ix[q] * 128 + lane * 2);
#pragma unroll
    for (int q = 0; q < 16; ++q) {
      a0 += __uint_as_float(u[q] << 16);
      a1 += __uint_as_float(u[q] & 0xFFFF0000u);
    }
  }
  if (j < e) {  // remainder exactly 8 (degrees padded to x8)
    int ix[8];
#pragma unroll
    for (int q = 0; q < 8; ++q) ix[q] = srcs[j + q];
    uint32_t u[8];
#pragma unroll
    for (int q = 0; q < 8; ++q)
      u[q] = *(const uint32_t*)(hlin + (size_t)ix[q] * 128 + lane * 2);
#pragma unroll
    for (int q = 0; q < 8; ++q) {
      a0 += __uint_as_float(u[q] << 16);
      a1 += __uint_as_float(u[q] & 0xFFFF0000u);
    }
  }
  float2 bv = ((const float2*)bias)[lane];
  size_t idx = (size_t)node * 128 + lane * 2;
  float h0, h1;
  if (first) {
    h0 = a0 + bv.x; h1 = a1 + bv.y;
  } else {
    uint32_t up = *(const uint32_t*)(hbf + idx);
    h0 = __uint_as_float(up << 16) + a0 + bv.x;
    h1 = __uint_as_float(up & 0xFFFF0000u) + a1 + bv.y;
  }
  if (last) {
    *(float2*)(outf + idx) = make_float2(h0, h1);
  } else {
    ushort2 r; r.x = f2b(h0); r.y = f2b(h1);
    *(ushort2*)(hbf + idx) = r;
  }
}

extern "C" void kernel_launch(void* const* d_in, const int* in_sizes, int n_in,
                              void* d_out, int out_size, void* d_ws, size_t ws_size,
                              hipStream_t stream) {
  const float* x = (const float*)d_in[0];
  const int* ei  = (const int*)d_in[1];
  const int* src = ei;
  const int* dst = ei + N_EDGES;
  const float* Wp[4] = {(const float*)d_in[4], (const float*)d_in[6],
                        (const float*)d_in[8], (const float*)d_in[10]};
  const float* bp[4] = {(const float*)d_in[5], (const float*)d_in[7],
                        (const float*)d_in[9], (const float*)d_in[11]};
  const int Kl[4] = {128, 256, 256, 256};

  char* w = (char*)d_ws;
  auto alloc = [&](size_t bytes) {
    char* p = w;
    w += (bytes + 255) & ~(size_t)255;
    return p;
  };
  ushort* x_bf     = (ushort*)alloc((size_t)N_NODES * 128 * 2);
  ushort* hbf      = (ushort*)alloc((size_t)N_NODES * 128 * 2);
  ushort* hlin     = (ushort*)alloc((size_t)(N_NODES + 8) * 128 * 2);  // +zero row
  int2*   off2     = (int2*)  alloc((size_t)N_NODES * 8);
  int*    srcs     = (int*)   alloc((size_t)SRCS_CAP * 4);
  int*    binned   = (int*)   alloc((size_t)NBUCK * BUCK_CAP * 4);
  int*    bucket_cnt  = (int*)alloc((size_t)NBUCK * 4);
  int*    bucket_base = (int*)alloc((size_t)NBUCK * 4);
  ushort* Wfr[4];
  for (int l = 0; l < 4; ++l) Wfr[l] = (ushort*)alloc((size_t)Kl[l] * 128 * 2);
  if ((size_t)(w - (char*)d_ws) > ws_size) return;

  hipMemsetAsync(bucket_cnt, 0, (size_t)NBUCK * 4, stream);
  hipMemsetAsync(hlin + (size_t)N_NODES * 128, 0, 256, stream);  // zero row for dummies
  k_cvt_bf16<<<2048, 256, 0, stream>>>(x, x_bf, N_NODES * 128 / 4);
  for (int l = 0; l < 4; ++l)
    k_cvtW<<<(Kl[l] * 128 + 255) / 256, 256, 0, stream>>>(Wp[l], Wfr[l], Kl[l]);
  k_bin<<<NB_BIN, 256, 0, stream>>>(src, dst, bucket_cnt, binned);
  k_bucket_scan<<<1, 256, 0, stream>>>(bucket_cnt, bucket_base);
  k_csr<<<NBUCK, 512, 0, stream>>>(binned, bucket_cnt, bucket_base, off2, srcs);

  int gblocks = (N_NODES + 127) / 128;
  int ablocks = (N_NODES + 3) / 4;
  // layer 0
  k_gemm<<<gblocks, 256, 0, stream>>>(x_bf, x_bf, Wfr[0], hlin, N_NODES, 128, 0);
  k_aggr<<<ablocks, 256, 0, stream>>>(hlin, off2, srcs, bp[0], hbf, (float*)d_out, N_NODES, 1, 0);
  // layers 1..2 full, layer 3 aggregation root-only (roots = nodes 0..4095)
  for (int l = 1; l < 4; ++l) {
    k_gemm<<<gblocks, 256, 0, stream>>>(hbf, x_bf, Wfr[l], hlin, N_NODES, 256, 1);
    if (l < 3) {
      k_aggr<<<ablocks, 256, 0, stream>>>(hlin, off2, srcs, bp[l], hbf, (float*)d_out,
                                          N_NODES, 0, 0);
    } else {
      k_aggr<<<(N_ROOTS + 3) / 4, 256, 0, stream>>>(hlin, off2, srcs, bp[l], hbf, (float*)d_out,
                                                    N_ROOTS, 0, 1);
    }
  }
}

// Round 16
// 361.331 us; speedup vs baseline: 1.6970x; 1.0078x over previous
//
#include <hip/hip_runtime.h>
#include <hip/hip_bf16.h>
#include <stdint.h>

#define N_NODES 100000
#define N_EDGES 1600000
#define FEAT 128
#define EMB 128
#define N_ROOTS 4096

#define BUCKET_BITS 9
#define BUCKET_NODES 512
#define NBUCK ((N_NODES + BUCKET_NODES - 1) / BUCKET_NODES)  // 196
#define BUCK_CAP 12288
#define BIN_CHUNK 4096
#define NB_BIN ((N_EDGES + BIN_CHUNK - 1) / BIN_CHUNK)       // 391
#define BUCK_SLACK 4096
#define SRCS_CAP (N_EDGES + NBUCK * BUCK_SLACK + 4096)

typedef __attribute__((ext_vector_type(4))) float f32x4;
typedef __attribute__((ext_vector_type(8))) short bf16x8;

__device__ __forceinline__ ushort f2b(float f) {
  uint32_t u = __float_as_uint(f);
  uint32_t r = (u + 0x7FFFu + ((u >> 16) & 1u)) >> 16;  // RNE
  return (ushort)r;
}

__global__ void k_cvt_bf16(const float* __restrict__ in, ushort* __restrict__ out, int n4) {
  int i = blockIdx.x * blockDim.x + threadIdx.x;
  int stride = gridDim.x * blockDim.x;
  for (; i < n4; i += stride) {
    float4 v = ((const float4*)in)[i];
    ushort4 o;
    o.x = f2b(v.x); o.y = f2b(v.y); o.z = f2b(v.z); o.w = f2b(v.w);
    ((ushort4*)out)[i] = o;
  }
}

// W (f32 [K][128]) -> bf16 pre-swizzled to GEMM LDS layout: byte = c*2K + ((2k)^((c&7)<<4))
__global__ void k_cvtW(const float* __restrict__ W, ushort* __restrict__ Wswz, int K) {
  int idx = blockIdx.x * blockDim.x + threadIdx.x;
  if (idx >= K * 128) return;
  int k = idx >> 7, c = idx & 127;
  ushort b = f2b(W[idx]);
  *(ushort*)((char*)Wswz + c * (K * 2) + ((k * 2) ^ ((c & 7) << 4))) = b;
}

// ---- bucketed CSR build (R11, unchanged) ----
__global__ __launch_bounds__(256) void k_bin(const int* __restrict__ srcA, const int* __restrict__ dstA,
                                             int* __restrict__ bucket_cnt, int* __restrict__ binned) {
  __shared__ int hist[NBUCK];
  __shared__ int lscan[NBUCK];
  __shared__ int rsv[NBUCK];
  __shared__ int lpos[NBUCK];
  __shared__ int ws[4];
  __shared__ int2 ent[BIN_CHUNK];
  int t = threadIdx.x;
  int e0 = blockIdx.x * BIN_CHUNK;
  int cnt = min(BIN_CHUNK, N_EDGES - e0);
  for (int i = t; i < NBUCK; i += 256) hist[i] = 0;
  __syncthreads();
  for (int j = t; j < cnt; j += 256) atomicAdd(&hist[dstA[e0 + j] >> BUCKET_BITS], 1);
  __syncthreads();
  {
    int lane = t & 63, wv = t >> 6;
    int v = (t < NBUCK) ? hist[t] : 0;
    int inc = v;
    for (int d = 1; d < 64; d <<= 1) { int x = __shfl_up(inc, d); if (lane >= d) inc += x; }
    if (lane == 63) ws[wv] = inc;
    __syncthreads();
    int wbase = 0;
    for (int k = 0; k < wv; ++k) wbase += ws[k];
    if (t < NBUCK) {
      int excl = wbase + inc - v;
      lscan[t] = excl;
      lpos[t] = excl;
      rsv[t] = (v > 0) ? atomicAdd(&bucket_cnt[t], v) : 0;
    }
  }
  __syncthreads();
  for (int j = t; j < cnt; j += 256) {
    int s = srcA[e0 + j], d = dstA[e0 + j];
    int p = atomicAdd(&lpos[d >> BUCKET_BITS], 1);
    ent[p] = make_int2(s, d);
  }
  __syncthreads();
  for (int j = t; j < cnt; j += 256) {
    int2 E = ent[j];
    int b = E.y >> BUCKET_BITS;
    int pos = rsv[b] + (j - lscan[b]);
    if (pos < BUCK_CAP)
      binned[b * BUCK_CAP + pos] = (E.x << BUCKET_BITS) | (E.y & (BUCKET_NODES - 1));
  }
}

__global__ __launch_bounds__(256) void k_bucket_scan(const int* __restrict__ bucket_cnt,
                                                     int* __restrict__ bucket_base) {
  __shared__ int ws[4];
  int t = threadIdx.x;
  int lane = t & 63, wv = t >> 6;
  int v = (t < NBUCK) ? bucket_cnt[t] : 0;
  int inc = v;
  for (int d = 1; d < 64; d <<= 1) { int x = __shfl_up(inc, d); if (lane >= d) inc += x; }
  if (lane == 63) ws[wv] = inc;
  __syncthreads();
  int wbase = 0;
  for (int k = 0; k < wv; ++k) wbase += ws[k];
  if (t < NBUCK) bucket_base[t] = (wbase + inc - v) + t * BUCK_SLACK;
}

__global__ __launch_bounds__(512) void k_csr(const int* __restrict__ binned,
                                             const int* __restrict__ bucket_cnt,
                                             const int* __restrict__ bucket_base,
                                             int2* __restrict__ off2, int* __restrict__ srcs) {
  __shared__ int deg[BUCKET_NODES];
  __shared__ int sAb[BUCKET_NODES];
  __shared__ int sBb[BUCKET_NODES];
  __shared__ int pos[BUCKET_NODES];
  __shared__ int epk[BUCK_CAP];
  int b = blockIdx.x;
  int t = threadIdx.x;
  int cnt = min(bucket_cnt[b], BUCK_CAP);
  int gbase = bucket_base[b];
  int n0 = b * BUCKET_NODES;
  int nn = min(BUCKET_NODES, N_NODES - n0);
  deg[t] = 0;
  __syncthreads();
  for (int j = t; j < cnt; j += 512) {
    int p = binned[b * BUCK_CAP + j];
    epk[j] = p;
    atomicAdd(&deg[p & (BUCKET_NODES - 1)], 1);
  }
  __syncthreads();
  int d = deg[t];
  int dp = (d + 7) & ~7;
  int* sA = sAb; int* sB = sBb;
  sA[t] = dp;
  __syncthreads();
  for (int q = 1; q < 512; q <<= 1) {
    int x = sA[t];
    if (t >= q) x += sA[t - q];
    sB[t] = x;
    __syncthreads();
    int* tp = sA; sA = sB; sB = tp;
  }
  int ex = sA[t] - dp;
  pos[t] = ex;
  if (t < nn) off2[n0 + t] = make_int2(gbase + ex, gbase + ex + dp);
  __syncthreads();
  for (int j = t; j < cnt; j += 512) {
    int p = epk[j];
    int q = atomicAdd(&pos[p & (BUCKET_NODES - 1)], 1);
    srcs[gbase + q] = p >> BUCKET_BITS;
  }
  __syncthreads();
  for (int q = ex + d; q < ex + dp; ++q) srcs[gbase + q] = N_NODES;  // zero-row dummies
}

// ---- S3 active set: {srcs of root edges} ∪ {roots}; deterministic compaction ----
__global__ __launch_bounds__(256) void k_flag(const int2* __restrict__ off2,
                                              const int* __restrict__ srcs, int* __restrict__ flag) {
  int root = blockIdx.x * 4 + (threadIdx.x >> 6);
  if (root >= N_ROOTS) return;
  int lane = threadIdx.x & 63;
  if (lane == 0) flag[root] = 1;
  int2 se = off2[root];
  for (int j = se.x + lane; j < se.y; j += 64) flag[srcs[j]] = 1;  // dummies hit flag[N_NODES]
}

__global__ __launch_bounds__(512) void k_scnt(const int* __restrict__ flag, int* __restrict__ bcnt) {
  __shared__ int ws[8];
  int b = blockIdx.x, t = threadIdx.x;
  int n0 = b * BUCKET_NODES;
  int nn = min(BUCKET_NODES, N_NODES - n0);
  int f = (t < nn) ? flag[n0 + t] : 0;
  int lane = t & 63, wv = t >> 6;
  int s = f;
  for (int q = 1; q < 64; q <<= 1) s += __shfl_xor(s, q);
  if (lane == 0) ws[wv] = s;
  __syncthreads();
  if (t == 0) {
    int tot = 0;
    for (int k = 0; k < 8; ++k) tot += ws[k];
    bcnt[b] = tot;
  }
}

__global__ __launch_bounds__(256) void k_sscan(const int* __restrict__ bcnt,
                                               int* __restrict__ bbase, int* __restrict__ cntP) {
  __shared__ int ws[4];
  int t = threadIdx.x;
  int lane = t & 63, wv = t >> 6;
  int v = (t < NBUCK) ? bcnt[t] : 0;
  int inc = v;
  for (int d = 1; d < 64; d <<= 1) { int x = __shfl_up(inc, d); if (lane >= d) inc += x; }
  if (lane == 63) ws[wv] = inc;
  __syncthreads();
  int wbase = 0;
  for (int k = 0; k < wv; ++k) wbase += ws[k];
  if (t < NBUCK) bbase[t] = wbase + inc - v;
  if (t == NBUCK - 1) *cntP = wbase + inc;
}

__global__ __launch_bounds__(512) void k_sscat(const int* __restrict__ flag,
                                               const int* __restrict__ bbase, int* __restrict__ list) {
  __shared__ int sAb[BUCKET_NODES];
  __shared__ int sBb[BUCKET_NODES];
  int b = blockIdx.x, t = threadIdx.x;
  int n0 = b * BUCKET_NODES;
  int nn = min(BUCKET_NODES, N_NODES - n0);
  int f = (t < nn) ? flag[n0 + t] : 0;
  int* sA = sAb; int* sB = sBb;
  sA[t] = f;
  __syncthreads();
  for (int q = 1; q < 512; q <<= 1) {
    int x = sA[t];
    if (t >= q) x += sA[t - q];
    sB[t] = x;
    __syncthreads();
    int* tp = sA; sA = sB; sB = tp;
  }
  if (f) list[bbase[b] + sA[t] - 1] = n0 + t;
}

// out[rows][128](bf16) = A @ W; A = A0|A1 split at k=128 (optional relu on A0);
// W pre-swizzled bf16 staged in LDS; optional row list (active-set mode).
__global__ __launch_bounds__(256) void k_gemm(
    const ushort* __restrict__ A0, const ushort* __restrict__ A1,
    const ushort* __restrict__ Wswz, ushort* __restrict__ out,
    const int* __restrict__ list, const int* __restrict__ cntP,
    int n, int K, int relu0)
{
  int nEff = n;
  if (list) {
    nEff = *cntP;
    if (blockIdx.x * 128 >= nEff) return;   // uniform block exit, before any barrier
  }
  extern __shared__ char smem[];
  int bytes = K * 256;
  for (int idx = threadIdx.x * 16; idx < bytes; idx += 256 * 16)
    *(uint4*)(smem + idx) = *(const uint4*)((const char*)Wswz + idx);
  __syncthreads();

  int lane = threadIdx.x & 63;
  int wv = threadIdx.x >> 6;
  int rowBase = blockIdx.x * 128 + wv * 32;
  int rl = lane & 15;
  int kh = lane >> 4;
  int r0 = min(rowBase + rl, nEff - 1), r1 = min(rowBase + rl + 16, nEff - 1);
  int n0 = list ? list[r0] : r0;
  int n1 = list ? list[r1] : r1;

  f32x4 acc[2][8];
#pragma unroll
  for (int i = 0; i < 2; ++i)
#pragma unroll
    for (int j = 0; j < 8; ++j)
      acc[i][j] = (f32x4){0.f, 0.f, 0.f, 0.f};

  int nks = K >> 5;
  bf16x8 a0, a1;
  {
    int kof = (kh << 3);
    a0 = *(const bf16x8*)(A0 + (size_t)n0 * 128 + kof);
    a1 = *(const bf16x8*)(A0 + (size_t)n1 * 128 + kof);
  }
  for (int ks = 0; ks < nks; ++ks) {
    bf16x8 na0 = a0, na1 = a1;
    if (ks + 1 < nks) {
      int ksn = ks + 1;
      const ushort* Asrc = (ksn < 4) ? A0 : A1;
      int kof = ((ksn & 3) << 5) + (kh << 3);
      na0 = *(const bf16x8*)(Asrc + (size_t)n0 * 128 + kof);
      na1 = *(const bf16x8*)(Asrc + (size_t)n1 * 128 + kof);
    }
    if (relu0 && ks < 4) {
#pragma unroll
      for (int q = 0; q < 8; ++q) {
        short v0 = a0[q]; a0[q] = (short)(v0 & ~(v0 >> 15));
        short v1 = a1[q]; a1[q] = (short)(v1 & ~(v1 >> 15));
      }
    }
    int kk = (ks << 5) + (kh << 3);
#pragma unroll
    for (int ct = 0; ct < 8; ++ct) {
      int col = (ct << 4) + rl;
      bf16x8 b = *(const bf16x8*)(smem + col * (K * 2) + ((kk * 2) ^ ((col & 7) << 4)));
      acc[0][ct] = __builtin_amdgcn_mfma_f32_16x16x32_bf16(a0, b, acc[0][ct], 0, 0, 0);
      acc[1][ct] = __builtin_amdgcn_mfma_f32_16x16x32_bf16(a1, b, acc[1][ct], 0, 0, 0);
    }
    a0 = na0; a1 = na1;
  }
#pragma unroll
  for (int ri = 0; ri < 2; ++ri)
#pragma unroll
    for (int ct = 0; ct < 8; ++ct) {
      int col = (ct << 4) + rl;
#pragma unroll
      for (int j = 0; j < 4; ++j) {
        int row = rowBase + ri * 16 + kh * 4 + j;
        if (row < nEff) {
          int orow = list ? list[row] : row;
          out[(size_t)orow * 128 + col] = f2b(acc[ri][ct][j]);
        }
      }
    }
}

// segment sum, padded CSR: 1 wave/node, 2 cols/lane, unroll-16; optional node list.
__global__ __launch_bounds__(256) void k_aggr(
    const ushort* __restrict__ hlin, const int2* __restrict__ off2, const int* __restrict__ srcs,
    const float* __restrict__ bias, ushort* __restrict__ hbf, float* __restrict__ outf,
    const int* __restrict__ list, const int* __restrict__ cntP,
    int n, int first, int last)
{
  int gid = blockIdx.x * 4 + (threadIdx.x >> 6);
  int node;
  if (list) {
    int cnt = *cntP;
    if (gid >= cnt) return;
    node = list[gid];
  } else {
    if (gid >= n) return;
    node = gid;
  }
  int lane = threadIdx.x & 63;
  int2 se = off2[node];
  int s = __builtin_amdgcn_readfirstlane(se.x);
  int e = __builtin_amdgcn_readfirstlane(se.y);
  float a0 = 0.f, a1 = 0.f;
  int j = s;
  for (; j + 16 <= e; j += 16) {
    int ix[16];
#pragma unroll
    for (int q = 0; q < 16; ++q) ix[q] = srcs[j + q];
    uint32_t u[16];
#pragma unroll
    for (int q = 0; q < 16; ++q)
      u[q] = *(const uint32_t*)(hlin + (size_t)ix[q] * 128 + lane * 2);
#pragma unroll
    for (int q = 0; q < 16; ++q) {
      a0 += __uint_as_float(u[q] << 16);
      a1 += __uint_as_float(u[q] & 0xFFFF0000u);
    }
  }
  if (j < e) {  // remainder exactly 8 (degrees padded to x8)
    int ix[8];
#pragma unroll
    for (int q = 0; q < 8; ++q) ix[q] = srcs[j + q];
    uint32_t u[8];
#pragma unroll
    for (int q = 0; q < 8; ++q)
      u[q] = *(const uint32_t*)(hlin + (size_t)ix[q] * 128 + lane * 2);
#pragma unroll
    for (int q = 0; q < 8; ++q) {
      a0 += __uint_as_float(u[q] << 16);
      a1 += __uint_as_float(u[q] & 0xFFFF0000u);
    }
  }
  float2 bv = ((const float2*)bias)[lane];
  size_t idx = (size_t)node * 128 + lane * 2;
  float h0, h1;
  if (first) {
    h0 = a0 + bv.x; h1 = a1 + bv.y;
  } else {
    uint32_t up = *(const uint32_t*)(hbf + idx);
    h0 = __uint_as_float(up << 16) + a0 + bv.x;
    h1 = __uint_as_float(up & 0xFFFF0000u) + a1 + bv.y;
  }
  if (last) {
    *(float2*)(outf + idx) = make_float2(h0, h1);
  } else {
    ushort2 r; r.x = f2b(h0); r.y = f2b(h1);
    *(ushort2*)(hbf + idx) = r;
  }
}

extern "C" void kernel_launch(void* const* d_in, const int* in_sizes, int n_in,
                              void* d_out, int out_size, void* d_ws, size_t ws_size,
                              hipStream_t stream) {
  const float* x = (const float*)d_in[0];
  const int* ei  = (const int*)d_in[1];
  const int* src = ei;
  const int* dst = ei + N_EDGES;
  const float* Wp[4] = {(const float*)d_in[4], (const float*)d_in[6],
                        (const float*)d_in[8], (const float*)d_in[10]};
  const float* bp[4] = {(const float*)d_in[5], (const float*)d_in[7],
                        (const float*)d_in[9], (const float*)d_in[11]};
  const int Kl[4] = {128, 256, 256, 256};

  char* w = (char*)d_ws;
  auto alloc = [&](size_t bytes) {
    char* p = w;
    w += (bytes + 255) & ~(size_t)255;
    return p;
  };
  ushort* x_bf     = (ushort*)alloc((size_t)N_NODES * 128 * 2);
  ushort* hbf      = (ushort*)alloc((size_t)N_NODES * 128 * 2);
  ushort* hlin     = (ushort*)alloc((size_t)(N_NODES + 8) * 128 * 2);  // +zero row
  int2*   off2     = (int2*)  alloc((size_t)N_NODES * 8);
  int*    srcs     = (int*)   alloc((size_t)SRCS_CAP * 4);
  int*    binned   = (int*)   alloc((size_t)NBUCK * BUCK_CAP * 4);
  int*    bucket_cnt  = (int*)alloc((size_t)NBUCK * 4);
  int*    bucket_base = (int*)alloc((size_t)NBUCK * 4);
  int*    flag     = (int*)   alloc((size_t)(N_NODES + 1) * 4);
  int*    slist    = (int*)   alloc((size_t)N_NODES * 4);
  int*    sbcnt    = (int*)   alloc((size_t)NBUCK * 4);
  int*    sbbase   = (int*)   alloc((size_t)NBUCK * 4);
  int*    scnt     = (int*)   alloc(256);
  ushort* Wswz[4];
  for (int l = 0; l < 4; ++l) Wswz[l] = (ushort*)alloc((size_t)Kl[l] * 128 * 2);
  if ((size_t)(w - (char*)d_ws) > ws_size) return;

  hipMemsetAsync(bucket_cnt, 0, (size_t)NBUCK * 4, stream);
  hipMemsetAsync(flag, 0, (size_t)(N_NODES + 1) * 4, stream);
  hipMemsetAsync(hlin + (size_t)N_NODES * 128, 0, 256, stream);  // zero row for dummies
  k_cvt_bf16<<<2048, 256, 0, stream>>>(x, x_bf, N_NODES * 128 / 4);
  for (int l = 0; l < 4; ++l)
    k_cvtW<<<(Kl[l] * 128 + 255) / 256, 256, 0, stream>>>(Wp[l], Wswz[l], Kl[l]);
  k_bin<<<NB_BIN, 256, 0, stream>>>(src, dst, bucket_cnt, binned);
  k_bucket_scan<<<1, 256, 0, stream>>>(bucket_cnt, bucket_base);
  k_csr<<<NBUCK, 512, 0, stream>>>(binned, bucket_cnt, bucket_base, off2, srcs);
  // S3 active set = {srcs of root edges} ∪ {roots}
  k_flag<<<(N_ROOTS + 3) / 4, 256, 0, stream>>>(off2, srcs, flag);
  k_scnt<<<NBUCK, 512, 0, stream>>>(flag, sbcnt);
  k_sscan<<<1, 256, 0, stream>>>(sbcnt, sbbase, scnt);
  k_sscat<<<NBUCK, 512, 0, stream>>>(flag, sbbase, slist);

  int gblocks = (N_NODES + 127) / 128;
  int ablocks = (N_NODES + 3) / 4;
  // layer 0: full
  k_gemm<<<gblocks, 256, 128 * 256, stream>>>(x_bf, x_bf, Wswz[0], hlin,
                                              nullptr, nullptr, N_NODES, 128, 0);
  k_aggr<<<ablocks, 256, 0, stream>>>(hlin, off2, srcs, bp[0], hbf, (float*)d_out,
                                      nullptr, nullptr, N_NODES, 1, 0);
  // layer 1: full
  k_gemm<<<gblocks, 256, 256 * 256, stream>>>(hbf, x_bf, Wswz[1], hlin,
                                              nullptr, nullptr, N_NODES, 256, 1);
  k_aggr<<<ablocks, 256, 0, stream>>>(hlin, off2, srcs, bp[1], hbf, (float*)d_out,
                                      nullptr, nullptr, N_NODES, 0, 0);
  // layer 2: gemm full (its output is gathered from ~all nodes), aggr restricted to S3
  k_gemm<<<gblocks, 256, 256 * 256, stream>>>(hbf, x_bf, Wswz[2], hlin,
                                              nullptr, nullptr, N_NODES, 256, 1);
  k_aggr<<<ablocks, 256, 0, stream>>>(hlin, off2, srcs, bp[2], hbf, (float*)d_out,
                                      slist, scnt, N_NODES, 0, 0);
  // layer 3: gemm over S3 rows only; aggr root-only -> d_out (f32)
  k_gemm<<<gblocks, 256, 256 * 256, stream>>>(hbf, x_bf, Wswz[3], hlin,
                                              slist, scnt, N_NODES, 256, 1);
  k_aggr<<<(N_ROOTS + 3) / 4, 256, 0, stream>>>(hlin, off2, srcs, bp[3], hbf, (float*)d_out,
                                                nullptr, nullptr, N_ROOTS, 0, 1);
}

// Round 17
// 345.795 us; speedup vs baseline: 1.7732x; 1.0449x over previous
//
#include <hip/hip_runtime.h>
#include <hip/hip_bf16.h>
#include <stdint.h>

#define N_NODES 100000
#define N_EDGES 1600000
#define FEAT 128
#define EMB 128
#define N_ROOTS 4096

#define BUCKET_BITS 9
#define BUCKET_NODES 512
#define NBUCK ((N_NODES + BUCKET_NODES - 1) / BUCKET_NODES)  // 196
#define BUCK_CAP 12288
#define BIN_CHUNK 4096
#define NB_BIN ((N_EDGES + BIN_CHUNK - 1) / BIN_CHUNK)       // 391
#define BUCK_SLACK 4096                                      // >= 512*7 pad slack per bucket
#define SRCS_CAP (N_EDGES + NBUCK * BUCK_SLACK + 4096)

typedef __attribute__((ext_vector_type(4))) float f32x4;
typedef __attribute__((ext_vector_type(8))) short bf16x8;

__device__ __forceinline__ ushort f2b(float f) {
  uint32_t u = __float_as_uint(f);
  uint32_t r = (u + 0x7FFFu + ((u >> 16) & 1u)) >> 16;  // RNE
  return (ushort)r;
}

__global__ void k_cvt_bf16(const float* __restrict__ in, ushort* __restrict__ out, int n4) {
  int i = blockIdx.x * blockDim.x + threadIdx.x;
  int stride = gridDim.x * blockDim.x;
  for (; i < n4; i += stride) {
    float4 v = ((const float4*)in)[i];
    ushort4 o;
    o.x = f2b(v.x); o.y = f2b(v.y); o.z = f2b(v.z); o.w = f2b(v.w);
    ((ushort4*)out)[i] = o;
  }
}

// W (f32 [K][128]) -> bf16, pre-swizzled to the GEMM LDS layout:
// byte addr = c*2K + ((2k) ^ ((c&7)<<4))
__global__ void k_cvtW(const float* __restrict__ W, ushort* __restrict__ Wswz, int K) {
  int idx = blockIdx.x * blockDim.x + threadIdx.x;
  if (idx >= K * 128) return;
  int k = idx >> 7, c = idx & 127;
  ushort b = f2b(W[idx]);
  *(ushort*)((char*)Wswz + c * (K * 2) + ((k * 2) ^ ((c & 7) << 4))) = b;
}

// ---- bucketed CSR build ----
__global__ __launch_bounds__(256) void k_bin(const int* __restrict__ srcA, const int* __restrict__ dstA,
                                             int* __restrict__ bucket_cnt, int* __restrict__ binned) {
  __shared__ int hist[NBUCK];
  __shared__ int lscan[NBUCK];
  __shared__ int rsv[NBUCK];
  __shared__ int lpos[NBUCK];
  __shared__ int ws[4];
  __shared__ int2 ent[BIN_CHUNK];
  int t = threadIdx.x;
  int e0 = blockIdx.x * BIN_CHUNK;
  int cnt = min(BIN_CHUNK, N_EDGES - e0);
  for (int i = t; i < NBUCK; i += 256) hist[i] = 0;
  __syncthreads();
  for (int j = t; j < cnt; j += 256) atomicAdd(&hist[dstA[e0 + j] >> BUCKET_BITS], 1);
  __syncthreads();
  {
    int lane = t & 63, wv = t >> 6;
    int v = (t < NBUCK) ? hist[t] : 0;
    int inc = v;
    for (int d = 1; d < 64; d <<= 1) { int x = __shfl_up(inc, d); if (lane >= d) inc += x; }
    if (lane == 63) ws[wv] = inc;
    __syncthreads();
    int wbase = 0;
    for (int k = 0; k < wv; ++k) wbase += ws[k];
    if (t < NBUCK) {
      int excl = wbase + inc - v;
      lscan[t] = excl;
      lpos[t] = excl;
      rsv[t] = (v > 0) ? atomicAdd(&bucket_cnt[t], v) : 0;
    }
  }
  __syncthreads();
  for (int j = t; j < cnt; j += 256) {
    int s = srcA[e0 + j], d = dstA[e0 + j];
    int p = atomicAdd(&lpos[d >> BUCKET_BITS], 1);
    ent[p] = make_int2(s, d);
  }
  __syncthreads();
  for (int j = t; j < cnt; j += 256) {
    int2 E = ent[j];
    int b = E.y >> BUCKET_BITS;
    int pos = rsv[b] + (j - lscan[b]);
    if (pos < BUCK_CAP)
      binned[b * BUCK_CAP + pos] = (E.x << BUCKET_BITS) | (E.y & (BUCKET_NODES - 1));
  }
}

// scan UNPADDED bucket counts; per-bucket base gets +b*BUCK_SLACK headroom for padding
__global__ __launch_bounds__(256) void k_bucket_scan(const int* __restrict__ bucket_cnt,
                                                     int* __restrict__ bucket_base) {
  __shared__ int ws[4];
  int t = threadIdx.x;
  int lane = t & 63, wv = t >> 6;
  int v = (t < NBUCK) ? bucket_cnt[t] : 0;
  int inc = v;
  for (int d = 1; d < 64; d <<= 1) { int x = __shfl_up(inc, d); if (lane >= d) inc += x; }
  if (lane == 63) ws[wv] = inc;
  __syncthreads();
  int wbase = 0;
  for (int k = 0; k < wv; ++k) wbase += ws[k];
  if (t < NBUCK) bucket_base[t] = (wbase + inc - v) + t * BUCK_SLACK;
}

// per-bucket: LDS degrees + padded scan + scatter + dummy fill; writes off2 = {start,end}
__global__ __launch_bounds__(512) void k_csr(const int* __restrict__ binned,
                                             const int* __restrict__ bucket_cnt,
                                             const int* __restrict__ bucket_base,
                                             int2* __restrict__ off2, int* __restrict__ srcs) {
  __shared__ int deg[BUCKET_NODES];
  __shared__ int sAb[BUCKET_NODES];
  __shared__ int sBb[BUCKET_NODES];
  __shared__ int pos[BUCKET_NODES];
  __shared__ int epk[BUCK_CAP];
  int b = blockIdx.x;
  int t = threadIdx.x;
  int cnt = min(bucket_cnt[b], BUCK_CAP);
  int gbase = bucket_base[b];
  int n0 = b * BUCKET_NODES;
  int nn = min(BUCKET_NODES, N_NODES - n0);
  deg[t] = 0;
  __syncthreads();
  for (int j = t; j < cnt; j += 512) {
    int p = binned[b * BUCK_CAP + j];
    epk[j] = p;
    atomicAdd(&deg[p & (BUCKET_NODES - 1)], 1);
  }
  __syncthreads();
  int d = deg[t];
  int dp = (d + 7) & ~7;
  int* sA = sAb; int* sB = sBb;
  sA[t] = dp;
  __syncthreads();
  for (int q = 1; q < 512; q <<= 1) {
    int x = sA[t];
    if (t >= q) x += sA[t - q];
    sB[t] = x;
    __syncthreads();
    int* tp = sA; sA = sB; sB = tp;
  }
  int ex = sA[t] - dp;   // exclusive padded scan
  pos[t] = ex;
  if (t < nn) off2[n0 + t] = make_int2(gbase + ex, gbase + ex + dp);
  __syncthreads();
  for (int j = t; j < cnt; j += 512) {
    int p = epk[j];
    int q = atomicAdd(&pos[p & (BUCKET_NODES - 1)], 1);
    srcs[gbase + q] = p >> BUCKET_BITS;
  }
  __syncthreads();
  for (int q = ex + d; q < ex + dp; ++q) srcs[gbase + q] = N_NODES;  // zero-row dummies
}

// out[n][128](bf16) = A @ W; A = A0|A1 split at k=128 (optional relu on A0);
// W pre-swizzled bf16; A-loads prefetched one k-step ahead.
__global__ __launch_bounds__(256) void k_gemm(
    const ushort* __restrict__ A0, const ushort* __restrict__ A1,
    const ushort* __restrict__ Wswz, ushort* __restrict__ out, int n, int K, int relu0)
{
  extern __shared__ char smem[];
  int bytes = K * 256;  // K*128*2
  for (int idx = threadIdx.x * 16; idx < bytes; idx += 256 * 16)
    *(uint4*)(smem + idx) = *(const uint4*)((const char*)Wswz + idx);
  __syncthreads();

  int lane = threadIdx.x & 63;
  int wv = threadIdx.x >> 6;
  int rowBase = blockIdx.x * 128 + wv * 32;
  int rl = lane & 15;
  int kh = lane >> 4;
  int r0 = rowBase + rl, r1 = r0 + 16;
  int r0c = min(r0, n - 1), r1c = min(r1, n - 1);

  f32x4 acc[2][8];
#pragma unroll
  for (int i = 0; i < 2; ++i)
#pragma unroll
    for (int j = 0; j < 8; ++j)
      acc[i][j] = (f32x4){0.f, 0.f, 0.f, 0.f};

  int nks = K >> 5;
  bf16x8 a0, a1;
  {
    const ushort* Asrc = A0;
    int kof = (kh << 3);
    a0 = *(const bf16x8*)(Asrc + (size_t)r0c * 128 + kof);
    a1 = *(const bf16x8*)(Asrc + (size_t)r1c * 128 + kof);
  }
  for (int ks = 0; ks < nks; ++ks) {
    bf16x8 na0 = a0, na1 = a1;
    if (ks + 1 < nks) {
      int ksn = ks + 1;
      const ushort* Asrc = (ksn < 4) ? A0 : A1;
      int kof = ((ksn & 3) << 5) + (kh << 3);
      na0 = *(const bf16x8*)(Asrc + (size_t)r0c * 128 + kof);
      na1 = *(const bf16x8*)(Asrc + (size_t)r1c * 128 + kof);
    }
    if (relu0 && ks < 4) {
#pragma unroll
      for (int q = 0; q < 8; ++q) {
        short v0 = a0[q]; a0[q] = (short)(v0 & ~(v0 >> 15));
        short v1 = a1[q]; a1[q] = (short)(v1 & ~(v1 >> 15));
      }
    }
    int kk = (ks << 5) + (kh << 3);
#pragma unroll
    for (int ct = 0; ct < 8; ++ct) {
      int col = (ct << 4) + rl;
      bf16x8 b = *(const bf16x8*)(smem + col * (K * 2) + ((kk * 2) ^ ((col & 7) << 4)));
      acc[0][ct] = __builtin_amdgcn_mfma_f32_16x16x32_bf16(a0, b, acc[0][ct], 0, 0, 0);
      acc[1][ct] = __builtin_amdgcn_mfma_f32_16x16x32_bf16(a1, b, acc[1][ct], 0, 0, 0);
    }
    a0 = na0; a1 = na1;
  }
#pragma unroll
  for (int ri = 0; ri < 2; ++ri)
#pragma unroll
    for (int ct = 0; ct < 8; ++ct) {
      int col = (ct << 4) + rl;
#pragma unroll
      for (int j = 0; j < 4; ++j) {
        int row = rowBase + ri * 16 + kh * 4 + j;
        if (row < n) out[(size_t)row * 128 + col] = f2b(acc[ri][ct][j]);
      }
    }
}

// segment sum, padded CSR: 1 wave/node, 2 cols/lane, unroll-16 two-phase
__global__ __launch_bounds__(256) void k_aggr(
    const ushort* __restrict__ hlin, const int2* __restrict__ off2, const int* __restrict__ srcs,
    const float* __restrict__ bias, ushort* __restrict__ hbf, float* __restrict__ outf,
    int n, int first, int last)
{
  int node = blockIdx.x * 4 + (threadIdx.x >> 6);
  if (node >= n) return;
  int lane = threadIdx.x & 63;
  int2 se = off2[node];
  int s = __builtin_amdgcn_readfirstlane(se.x);
  int e = __builtin_amdgcn_readfirstlane(se.y);
  float a0 = 0.f, a1 = 0.f;
  int j = s;
  for (; j + 16 <= e; j += 16) {
    int ix[16];
#pragma unroll
    for (int q = 0; q < 16; ++q) ix[q] = srcs[j + q];
    uint32_t u[16];
#pragma unroll
    for (int q = 0; q < 16; ++q)
      u[q] = *(const uint32_t*)(hlin + (size_t)ix[q] * 128 + lane * 2);
#pragma unroll
    for (int q = 0; q < 16; ++q) {
      a0 += __uint_as_float(u[q] << 16);
      a1 += __uint_as_float(u[q] & 0xFFFF0000u);
    }
  }
  if (j < e) {  // remainder exactly 8 (degrees padded to x8)
    int ix[8];
#pragma unroll
    for (int q = 0; q < 8; ++q) ix[q] = srcs[j + q];
    uint32_t u[8];
#pragma unroll
    for (int q = 0; q < 8; ++q)
      u[q] = *(const uint32_t*)(hlin + (size_t)ix[q] * 128 + lane * 2);
#pragma unroll
    for (int q = 0; q < 8; ++q) {
      a0 += __uint_as_float(u[q] << 16);
      a1 += __uint_as_float(u[q] & 0xFFFF0000u);
    }
  }
  float2 bv = ((const float2*)bias)[lane];
  size_t idx = (size_t)node * 128 + lane * 2;
  float h0, h1;
  if (first) {
    h0 = a0 + bv.x; h1 = a1 + bv.y;
  } else {
    uint32_t up = *(const uint32_t*)(hbf + idx);
    h0 = __uint_as_float(up << 16) + a0 + bv.x;
    h1 = __uint_as_float(up & 0xFFFF0000u) + a1 + bv.y;
  }
  if (last) {
    *(float2*)(outf + idx) = make_float2(h0, h1);
  } else {
    ushort2 r; r.x = f2b(h0); r.y = f2b(h1);
    *(ushort2*)(hbf + idx) = r;
  }
}

extern "C" void kernel_launch(void* const* d_in, const int* in_sizes, int n_in,
                              void* d_out, int out_size, void* d_ws, size_t ws_size,
                              hipStream_t stream) {
  const float* x = (const float*)d_in[0];
  const int* ei  = (const int*)d_in[1];
  const int* src = ei;
  const int* dst = ei + N_EDGES;
  const float* Wp[4] = {(const float*)d_in[4], (const float*)d_in[6],
                        (const float*)d_in[8], (const float*)d_in[10]};
  const float* bp[4] = {(const float*)d_in[5], (const float*)d_in[7],
                        (const float*)d_in[9], (const float*)d_in[11]};
  const int Kl[4] = {128, 256, 256, 256};

  char* w = (char*)d_ws;
  auto alloc = [&](size_t bytes) {
    char* p = w;
    w += (bytes + 255) & ~(size_t)255;
    return p;
  };
  ushort* x_bf     = (ushort*)alloc((size_t)N_NODES * 128 * 2);
  ushort* hbf      = (ushort*)alloc((size_t)N_NODES * 128 * 2);
  ushort* hlin     = (ushort*)alloc((size_t)(N_NODES + 8) * 128 * 2);  // +zero row
  int2*   off2     = (int2*)  alloc((size_t)N_NODES * 8);
  int*    srcs     = (int*)   alloc((size_t)SRCS_CAP * 4);
  int*    binned   = (int*)   alloc((size_t)NBUCK * BUCK_CAP * 4);
  int*    bucket_cnt  = (int*)alloc((size_t)NBUCK * 4);
  int*    bucket_base = (int*)alloc((size_t)NBUCK * 4);
  ushort* Wswz[4];
  for (int l = 0; l < 4; ++l) Wswz[l] = (ushort*)alloc((size_t)Kl[l] * 128 * 2);
  if ((size_t)(w - (char*)d_ws) > ws_size) return;

  hipMemsetAsync(bucket_cnt, 0, (size_t)NBUCK * 4, stream);
  hipMemsetAsync(hlin + (size_t)N_NODES * 128, 0, 256, stream);  // zero row for dummies
  k_cvt_bf16<<<2048, 256, 0, stream>>>(x, x_bf, N_NODES * 128 / 4);
  for (int l = 0; l < 4; ++l)
    k_cvtW<<<(Kl[l] * 128 + 255) / 256, 256, 0, stream>>>(Wp[l], Wswz[l], Kl[l]);
  k_bin<<<NB_BIN, 256, 0, stream>>>(src, dst, bucket_cnt, binned);
  k_bucket_scan<<<1, 256, 0, stream>>>(bucket_cnt, bucket_base);
  k_csr<<<NBUCK, 512, 0, stream>>>(binned, bucket_cnt, bucket_base, off2, srcs);

  int gblocks = (N_NODES + 127) / 128;
  int ablocks = (N_NODES + 3) / 4;
  // layer 0
  k_gemm<<<gblocks, 256, 128 * 128 * 2, stream>>>(x_bf, x_bf, Wswz[0], hlin, N_NODES, 128, 0);
  k_aggr<<<ablocks, 256, 0, stream>>>(hlin, off2, srcs, bp[0], hbf, (float*)d_out, N_NODES, 1, 0);
  // layers 1..2 full, layer 3 aggregation root-only (roots = nodes 0..4095)
  for (int l = 1; l < 4; ++l) {
    k_gemm<<<gblocks, 256, 256 * 128 * 2, stream>>>(hbf, x_bf, Wswz[l], hlin, N_NODES, 256, 1);
    if (l < 3) {
      k_aggr<<<ablocks, 256, 0, stream>>>(hlin, off2, srcs, bp[l], hbf, (float*)d_out,
                                          N_NODES, 0, 0);
    } else {
      k_aggr<<<(N_ROOTS + 3) / 4, 256, 0, stream>>>(hlin, off2, srcs, bp[l], hbf, (float*)d_out,
                                                    N_ROOTS, 0, 1);
    }
  }
}